// Round 8
// baseline (36.944 us; speedup 1.0000x reference)
//
#include <hip/hip_runtime.h>
#include <math.h>

#define D 64
#define DH 32

typedef __attribute__((ext_vector_type(8))) short bf16x8;   // MFMA A/B frag (4 VGPRs)
typedef __attribute__((ext_vector_type(4))) float f32x4;    // MFMA C/D frag

// fp32 -> bf16 RNE
static __device__ __forceinline__ unsigned short f2b(float f) {
    unsigned int u = __builtin_bit_cast(unsigned int, f);
    u += 0x7FFFu + ((u >> 16) & 1u);
    return (unsigned short)(u >> 16);
}
static __device__ __forceinline__ unsigned int pack_b2(float a, float b) {
    return (unsigned int)f2b(a) | ((unsigned int)f2b(b) << 16);
}
static __device__ __forceinline__ float gelu_exact(float v) {
    return 0.5f * v * (1.0f + erff(v * 0.70710678118654752f));
}
// async global->LDS, 16B per lane; lds dest must be wave-uniform base
static __device__ __forceinline__ void gload_lds16(void* l, const void* g) {
    __builtin_amdgcn_global_load_lds(
        (const __attribute__((address_space(1))) unsigned int*)g,
        (__attribute__((address_space(3))) unsigned int*)l, 16, 0, 0);
}

// ---------------------------------------------------------------------------
// Softmax over each row-segment sums to exactly 1, so
//   out[i] = has_edge(i) ? h[i]*(1+peak[i]) + bias : bias
// ---------------------------------------------------------------------------
__global__ void edge_flag_kernel(const int* __restrict__ row,
                                 unsigned char* __restrict__ flag, int E) {
    int i4 = (blockIdx.x * blockDim.x + threadIdx.x) * 4;
    if (i4 + 3 < E) {
        int4 r = *(const int4*)(row + i4);
        if (!flag[r.x]) flag[r.x] = 1;
        if (!flag[r.y]) flag[r.y] = 1;
        if (!flag[r.z]) flag[r.z] = 1;
        if (!flag[r.w]) flag[r.w] = 1;
    } else if (i4 < E) {
        for (int j = i4; j < E; ++j) flag[row[j]] = 1;
    }
}

// ---------------------------------------------------------------------------
// Prep: grid-stride zero of byte-flags + (block 0) pack per-lane MFMA frags
// into 20 contiguous 1KB chunks: [0..8) AW, [8..12) AW1, [12..16) bias,
// [16..18) b1, [18..20) W2.  Chunk f, lane l -> bytes f*1024 + l*16.
// ---------------------------------------------------------------------------
__global__ void prep_kernel(const float* __restrict__ Wlin, const float* __restrict__ W1,
                            const float* __restrict__ bias, const float* __restrict__ b1,
                            const float* __restrict__ W2,
                            uint4* __restrict__ flag4, int nflag4,
                            unsigned short* __restrict__ packAW,
                            unsigned short* __restrict__ packAW1, float* __restrict__ packBias,
                            float* __restrict__ packB1, float* __restrict__ packW2)
{
    const int idx = blockIdx.x * blockDim.x + threadIdx.x;
    const int stride = gridDim.x * blockDim.x;
    const uint4 z = {0u, 0u, 0u, 0u};
    for (int i = idx; i < nflag4; i += stride) flag4[i] = z;

    if (blockIdx.x == 0) {
        const int lane = threadIdx.x & 63, part = threadIdx.x >> 6;  // 4 parts
        const int q = lane >> 4, m = lane & 15;
#pragma unroll
        for (int fo = 0; fo < 2; ++fo) {                 // packAW: frags 2*part, 2*part+1
            const int f = part * 2 + fo, nt = f >> 1, ks = f & 1;
#pragma unroll
            for (int j = 0; j < 8; ++j) {
                const int k = 32 * ks + 8 * q + j, n = 16 * nt + m;
                packAW[(f * 64 + lane) * 8 + j] = f2b(Wlin[k * D + n]);
            }
        }
        {                                                 // packAW1: frag = part
            const int f = part, ntW = f >> 1, ks = f & 1;
#pragma unroll
            for (int j = 0; j < 8; ++j) {
                const int k = 32 * ks + 8 * q + j, n = 16 * ntW + m;
                packAW1[(f * 64 + lane) * 8 + j] = f2b(W1[k * DH + n]);
            }
        }
#pragma unroll
        for (int r = 0; r < 4; ++r)                       // packBias: nt = part
            packBias[(part * 64 + lane) * 4 + r] = bias[16 * part + 4 * q + r];
        if (part < 2) {
#pragma unroll
            for (int r = 0; r < 4; ++r)
                packB1[(part * 64 + lane) * 4 + r] = b1[16 * part + 4 * q + r];
        } else {
#pragma unroll
            for (int r = 0; r < 4; ++r)
                packW2[((part - 2) * 64 + lane) * 4 + r] = W2[16 * (part - 2) + 4 * q + r];
        }
    }
}

// ---------------------------------------------------------------------------
// Main: 256 thr = 4 waves, 128 nodes/block (32/wave, mt=2).  All staging via
// global_load_lds (no VGPR load destinations -> no pressure-driven vmcnt
// serialization): x tile 32KB chunk-XOR-swizzled (pre-swizzled global src,
// swizzled LDS read), pack 20KB linear.  One barrier.  h roundtrip overlays
// the wave-private x region (no extra LDS, no barrier).
// ---------------------------------------------------------------------------
__global__ __launch_bounds__(256) void gat_mfma4(
    const float* __restrict__ x, const unsigned char* __restrict__ flag,
    const float* __restrict__ packbuf, const float* __restrict__ b2,
    float* __restrict__ out, int N)
{
    __shared__ unsigned char lds[53248];   // [0,32K): x/h per-wave 8KB; [32K,52K): pack

    const int tid  = threadIdx.x;
    const int wv   = tid >> 6;
    const int lane = tid & 63;
    const int q    = lane >> 4;
    const int m    = lane & 15;
    const int nodeBase = blockIdx.x * 128 + wv * 32;
    const int XB = wv * 8192;

    // ---- early scalar-ish loads (drained by the barrier's vmcnt(0)) ----
    unsigned char fl[2];
#pragma unroll
    for (int mt = 0; mt < 2; ++mt) {
        int g = nodeBase + 16 * mt + m;
        if (g > N - 1) g = N - 1;
        fl[mt] = flag[g];
    }
    const float b2s = b2[0];

    // ---- stage x tile: 8 DMA/wave, 16B/lane; source pre-swizzled so LDS
    //      chunk c' of row r holds x[row][c' ^ (r&7)] ----
#pragma unroll
    for (int j = 0; j < 8; ++j) {
        const int r_loc = j * 4 + (lane >> 4);
        int grow = nodeBase + r_loc;
        if (grow > N - 1) grow = N - 1;
        const int c = lane & 15;
        const float* src = x + (size_t)grow * D + ((c ^ (r_loc & 7)) * 4);
        gload_lds16(lds + XB + j * 1024, src);
    }
    // ---- stage pack: 5 DMA/wave, linear ----
#pragma unroll
    for (int i = 0; i < 5; ++i) {
        const int ch = wv * 5 + i;
        gload_lds16(lds + 32768 + ch * 1024, packbuf + ch * 256 + lane * 4);
    }
    __syncthreads();   // drains vmcnt(0): all DMA + flag loads complete

    // ---- W^T A-frags from pack LDS ----
    bf16x8 aw[4][2];
#pragma unroll
    for (int nt = 0; nt < 4; ++nt)
#pragma unroll
        for (int ks = 0; ks < 2; ++ks)
            aw[nt][ks] = *(const bf16x8*)(lds + 32768 + (nt * 2 + ks) * 1024 + lane * 16);

    // ---- x B-frags from swizzled LDS + cvt to bf16 ----
    bf16x8 bx[2][2];
#pragma unroll
    for (int mt = 0; mt < 2; ++mt) {
        const int r = 16 * mt + m;
#pragma unroll
        for (int ks = 0; ks < 2; ++ks) {
            const int c0 = ks * 8 + q * 2;
            const uint4 lo = *(const uint4*)(lds + XB + r * 256 + ((c0 ^ (r & 7)) * 16));
            const uint4 hi = *(const uint4*)(lds + XB + r * 256 + (((c0 + 1) ^ (r & 7)) * 16));
            const float4 u0 = __builtin_bit_cast(float4, lo);
            const float4 u1 = __builtin_bit_cast(float4, hi);
            uint4 pk;
            pk.x = pack_b2(u0.x, u0.y); pk.y = pack_b2(u0.z, u0.w);
            pk.z = pack_b2(u1.x, u1.y); pk.w = pack_b2(u1.z, u1.w);
            bx[mt][ks] = __builtin_bit_cast(bf16x8, pk);
        }
    }

    // ---- GEMM1: h^T = W^T @ x^T ----
    f32x4 accH[2][4];
#pragma unroll
    for (int mt = 0; mt < 2; ++mt)
#pragma unroll
        for (int nt = 0; nt < 4; ++nt)
            accH[mt][nt] = (f32x4){0.f, 0.f, 0.f, 0.f};
#pragma unroll
    for (int ks = 0; ks < 2; ++ks)
#pragma unroll
        for (int mt = 0; mt < 2; ++mt)
#pragma unroll
            for (int nt = 0; nt < 4; ++nt)
                accH[mt][nt] = __builtin_amdgcn_mfma_f32_16x16x32_bf16(
                    aw[nt][ks], bx[mt][ks], accH[mt][nt], 0, 0, 0);
    // lane holds h[node=nodeBase+16mt+m][hcol=16nt+4q+r]

    // ---- h -> wave-private LDS overlay of the x region (bf16 [32][72]) ----
    asm volatile("" ::: "memory");   // x reads must precede sH writes
#pragma unroll
    for (int mt = 0; mt < 2; ++mt)
#pragma unroll
        for (int nt = 0; nt < 4; ++nt) {
            uint2 pk;
            pk.x = pack_b2(accH[mt][nt][0], accH[mt][nt][1]);
            pk.y = pack_b2(accH[mt][nt][2], accH[mt][nt][3]);
            *(uint2*)(lds + XB + (16 * mt + m) * 144 + (16 * nt + 4 * q) * 2) = pk;
        }
    asm volatile("" ::: "memory");   // sH writes must precede a2 reads
    bf16x8 a2[2][2];
#pragma unroll
    for (int mt = 0; mt < 2; ++mt)
#pragma unroll
        for (int ks = 0; ks < 2; ++ks)
            a2[mt][ks] = *(const bf16x8*)(lds + XB + (16 * mt + m) * 144 + (32 * ks + 8 * q) * 2);

    // ---- GEMM2: t^T = W1^T @ h^T ----
    bf16x8 aw1[2][2];
#pragma unroll
    for (int nt = 0; nt < 2; ++nt)
#pragma unroll
        for (int ks = 0; ks < 2; ++ks)
            aw1[nt][ks] = *(const bf16x8*)(lds + 32768 + (8 + nt * 2 + ks) * 1024 + lane * 16);
    const f32x4 b1v0 = *(const f32x4*)(lds + 32768 + 16 * 1024 + lane * 16);
    const f32x4 b1v1 = *(const f32x4*)(lds + 32768 + 17 * 1024 + lane * 16);
    f32x4 acc2[2][2];   // [ntW][mt]
    acc2[0][0] = b1v0; acc2[0][1] = b1v0;
    acc2[1][0] = b1v1; acc2[1][1] = b1v1;
#pragma unroll
    for (int ks = 0; ks < 2; ++ks)
#pragma unroll
        for (int nt = 0; nt < 2; ++nt)
#pragma unroll
            for (int mt = 0; mt < 2; ++mt)
                acc2[nt][mt] = __builtin_amdgcn_mfma_f32_16x16x32_bf16(
                    aw1[nt][ks], a2[mt][ks], acc2[nt][mt], 0, 0, 0);
    // lane holds t[node=nodeBase+16mt+m][w1col=16ntW+4q+r]

    // ---- peak: pp = sum gelu(t)*W2, reduce over the 4 q-groups ----
    const f32x4 w2v0 = *(const f32x4*)(lds + 32768 + 18 * 1024 + lane * 16);
    const f32x4 w2v1 = *(const f32x4*)(lds + 32768 + 19 * 1024 + lane * 16);
    float scale[2];
#pragma unroll
    for (int mt = 0; mt < 2; ++mt) {
        float pp = 0.f;
#pragma unroll
        for (int r = 0; r < 4; ++r) {
            pp = fmaf(gelu_exact(acc2[0][mt][r]), w2v0[r], pp);
            pp = fmaf(gelu_exact(acc2[1][mt][r]), w2v1[r], pp);
        }
        pp += __shfl_xor(pp, 16);
        pp += __shfl_xor(pp, 32);
        scale[mt] = (fl[mt] != 0) ? (1.f + 1.f / (1.f + expf(-(pp + b2s)))) : 0.f;
    }

    // ---- epilogue: out[node][16nt+4q+r] = h*scale + bias ----
    f32x4 biasv[4];
#pragma unroll
    for (int nt = 0; nt < 4; ++nt)
        biasv[nt] = *(const f32x4*)(lds + 32768 + (12 + nt) * 1024 + lane * 16);
#pragma unroll
    for (int mt = 0; mt < 2; ++mt) {
        const int g = nodeBase + 16 * mt + m;
        if (g < N) {
            float* po = out + (size_t)g * D + 4 * q;
#pragma unroll
            for (int nt = 0; nt < 4; ++nt) {
                f32x4 o;
#pragma unroll
                for (int r = 0; r < 4; ++r)
                    o[r] = fmaf(accH[mt][nt][r], scale[mt], biasv[nt][r]);
                *(f32x4*)(po + 16 * nt) = o;
            }
        }
    }
}

extern "C" void kernel_launch(void* const* d_in, const int* in_sizes, int n_in,
                              void* d_out, int out_size, void* d_ws, size_t ws_size,
                              hipStream_t stream) {
    const float* x    = (const float*)d_in[0];
    const int*   eidx = (const int*)d_in[1];   // [2, E]: first E entries = row
    const float* Wlin = (const float*)d_in[2];
    // d_in[3] att_src, d_in[4] att_dst cancel (segment softmax sums to 1)
    const float* bias = (const float*)d_in[5];
    const float* W1   = (const float*)d_in[6];
    const float* b1   = (const float*)d_in[7];
    const float* W2   = (const float*)d_in[8];
    const float* b2   = (const float*)d_in[9];
    float* out = (float*)d_out;

    const int N = in_sizes[0] / D;
    const int E = in_sizes[1] / 2;

    char* ws = (char*)d_ws;
    unsigned char* flag = (unsigned char*)ws;
    const int nflag4 = (N + 15) / 16;
    const size_t off = (((size_t)nflag4 * 16) + 255) & ~(size_t)255;
    unsigned short* packAW   = (unsigned short*)(ws + off);            // 8192 B (chunks 0-7)
    unsigned short* packAW1  = (unsigned short*)(ws + off + 8192);     // 4096 B (chunks 8-11)
    float*          packBias = (float*)(ws + off + 12288);             // 4096 B (chunks 12-15)
    float*          packB1   = (float*)(ws + off + 16384);             // 2048 B (chunks 16-17)
    float*          packW2   = (float*)(ws + off + 18432);             // 2048 B (chunks 18-19)
    const float*    packbuf  = (const float*)(ws + off);               // 20 KB contiguous

    prep_kernel<<<128, 256, 0, stream>>>(Wlin, W1, bias, b1, W2,
                                         (uint4*)flag, nflag4,
                                         packAW, packAW1, packBias, packB1, packW2);
    edge_flag_kernel<<<(E / 4 + 255) / 256, 256, 0, stream>>>(eidx, flag, E);
    gat_mfma4<<<(N + 127) / 128, 256, 0, stream>>>(x, flag, packbuf, b2, out, N);
}

// Round 9
// 31.548 us; speedup vs baseline: 1.1710x; 1.1710x over previous
//
#include <hip/hip_runtime.h>
#include <math.h>

#define D 64
#define DH 32

typedef __attribute__((ext_vector_type(8))) short bf16x8;   // MFMA A/B frag (4 VGPRs)
typedef __attribute__((ext_vector_type(4))) float f32x4;    // MFMA C/D frag

// fp32 -> bf16 RNE
static __device__ __forceinline__ unsigned short f2b(float f) {
    unsigned int u = __builtin_bit_cast(unsigned int, f);
    u += 0x7FFFu + ((u >> 16) & 1u);
    return (unsigned short)(u >> 16);
}
static __device__ __forceinline__ unsigned int pack_b2(float a, float b) {
    return (unsigned int)f2b(a) | ((unsigned int)f2b(b) << 16);
}
// A&S 7.1.26 erf (|err| < 1.5e-7): 1 rcp + 1 exp + ~10 fma, no branches
static __device__ __forceinline__ float gelu_fast(float v) {
    const float ax = fabsf(v) * 0.70710678118654752f;
    const float t  = __builtin_amdgcn_rcpf(fmaf(0.3275911f, ax, 1.0f));
    float poly = fmaf(1.061405429f, t, -1.453152027f);
    poly = fmaf(poly, t, 1.421413741f);
    poly = fmaf(poly, t, -0.284496736f);
    poly = fmaf(poly, t, 0.254829592f);
    poly *= t;
    float er = fmaf(-poly, __expf(-ax * ax), 1.0f);
    er = copysignf(er, v);
    return 0.5f * v * (1.0f + er);
}

// ---------------------------------------------------------------------------
// Softmax over each row-segment sums to exactly 1, so
//   out[i] = has_edge(i) ? h[i]*(1+peak[i]) + bias : bias
// ---------------------------------------------------------------------------
__global__ void edge_flag_kernel(const int* __restrict__ row,
                                 unsigned char* __restrict__ flag, int E) {
    int i4 = (blockIdx.x * blockDim.x + threadIdx.x) * 4;
    if (i4 + 3 < E) {
        int4 r = *(const int4*)(row + i4);
        flag[r.x] = 1; flag[r.y] = 1; flag[r.z] = 1; flag[r.w] = 1;
    } else if (i4 < E) {
        for (int j = i4; j < E; ++j) flag[row[j]] = 1;
    }
}

// ---------------------------------------------------------------------------
// Prep: grid-stride zero of byte-flags + (block 0) pack per-lane MFMA frags.
// Layout identical to r5 (verified): packAW 8 frags, packAW1 4, bias/b1/W2.
// ---------------------------------------------------------------------------
__global__ void prep_kernel(const float* __restrict__ Wlin, const float* __restrict__ W1,
                            const float* __restrict__ bias, const float* __restrict__ b1,
                            const float* __restrict__ W2,
                            uint4* __restrict__ flag4, int nflag4,
                            unsigned short* __restrict__ packAW,
                            unsigned short* __restrict__ packAW1, float* __restrict__ packBias,
                            float* __restrict__ packB1, float* __restrict__ packW2)
{
    const int idx = blockIdx.x * blockDim.x + threadIdx.x;
    const int stride = gridDim.x * blockDim.x;
    const uint4 z = {0u, 0u, 0u, 0u};
    for (int i = idx; i < nflag4; i += stride) flag4[i] = z;

    if (blockIdx.x == 0) {
        const int lane = threadIdx.x & 63, part = threadIdx.x >> 6;  // 4 parts
        const int q = lane >> 4, m = lane & 15;
#pragma unroll
        for (int fo = 0; fo < 2; ++fo) {
            const int f = part * 2 + fo, nt = f >> 1, ks = f & 1;
#pragma unroll
            for (int j = 0; j < 8; ++j) {
                const int k = 32 * ks + 8 * q + j, n = 16 * nt + m;
                packAW[(f * 64 + lane) * 8 + j] = f2b(Wlin[k * D + n]);
            }
        }
        {
            const int f = part, ntW = f >> 1, ks = f & 1;
#pragma unroll
            for (int j = 0; j < 8; ++j) {
                const int k = 32 * ks + 8 * q + j, n = 16 * ntW + m;
                packAW1[(f * 64 + lane) * 8 + j] = f2b(W1[k * DH + n]);
            }
        }
#pragma unroll
        for (int r = 0; r < 4; ++r)
            packBias[(part * 64 + lane) * 4 + r] = bias[16 * part + 4 * q + r];
        if (part < 2) {
#pragma unroll
            for (int r = 0; r < 4; ++r)
                packB1[(part * 64 + lane) * 4 + r] = b1[16 * part + 4 * q + r];
        } else {
#pragma unroll
            for (int r = 0; r < 4; ++r)
                packW2[((part - 2) * 64 + lane) * 4 + r] = W2[16 * (part - 2) + 4 * q + r];
        }
    }
}

// ---------------------------------------------------------------------------
// Main: PERSISTENT grid-stride kernel.  512 blocks x 4 waves; tile = 64 nodes
// (16/wave).  All weight frags hoisted to registers before the loop; compact
// hot loop (I-cache resident): x-prefetch(next) || {cvt, 8+4 MFMA, wave-
// private LDS roundtrip, gelu-dot, epilogue store}.  No barriers anywhere.
// ---------------------------------------------------------------------------
__global__ __launch_bounds__(256) void gat_mfma5(
    const float* __restrict__ x, const unsigned char* __restrict__ flag,
    const unsigned short* __restrict__ packAW, const unsigned short* __restrict__ packAW1,
    const float* __restrict__ packBias, const float* __restrict__ packB1,
    const float* __restrict__ packW2, const float* __restrict__ b2,
    float* __restrict__ out, int N, int ntiles)
{
    __shared__ unsigned short sH[4][16][72];   // per-wave h bf16, 9 KB

    const int tid  = threadIdx.x;
    const int wv   = tid >> 6;
    const int lane = tid & 63;
    const int q    = lane >> 4;
    const int m    = lane & 15;

    // ---- hoist all weight fragments into registers (loaded once, L2-hot) ----
    bf16x8 aw[4][2], aw1[2][2];
#pragma unroll
    for (int nt = 0; nt < 4; ++nt)
#pragma unroll
        for (int ks = 0; ks < 2; ++ks)
            aw[nt][ks] = ((const bf16x8*)packAW)[(nt * 2 + ks) * 64 + lane];
#pragma unroll
    for (int nt = 0; nt < 2; ++nt)
#pragma unroll
        for (int ks = 0; ks < 2; ++ks)
            aw1[nt][ks] = ((const bf16x8*)packAW1)[(nt * 2 + ks) * 64 + lane];
    const f32x4 b1v0 = ((const f32x4*)packB1)[0 * 64 + lane];
    const f32x4 b1v1 = ((const f32x4*)packB1)[1 * 64 + lane];
    const f32x4 w2v0 = ((const f32x4*)packW2)[0 * 64 + lane];
    const f32x4 w2v1 = ((const f32x4*)packW2)[1 * 64 + lane];
    f32x4 biasv[4];
#pragma unroll
    for (int nt = 0; nt < 4; ++nt) biasv[nt] = ((const f32x4*)packBias)[nt * 64 + lane];
    const float b2s = b2[0];

    int t = blockIdx.x;
    if (t >= ntiles) return;

    // ---- load tile t (cur) ----
    float4 cu0, cu1, cu2, cu3; unsigned char cfl;
    {
        int g = t * 64 + wv * 16 + m; if (g > N - 1) g = N - 1;
        const float* px = x + (size_t)g * D + 8 * q;
        cu0 = *(const float4*)(px);      cu1 = *(const float4*)(px + 4);
        cu2 = *(const float4*)(px + 32); cu3 = *(const float4*)(px + 36);
        cfl = flag[g];
    }

    while (true) {
        const int tn = t + gridDim.x;
        const bool more = tn < ntiles;
        // ---- prefetch tile tn (issued before compute; drains during MFMA) ----
        float4 nu0, nu1, nu2, nu3; unsigned char nfl = 0;
        if (more) {
            int g = tn * 64 + wv * 16 + m; if (g > N - 1) g = N - 1;
            const float* px = x + (size_t)g * D + 8 * q;
            nu0 = *(const float4*)(px);      nu1 = *(const float4*)(px + 4);
            nu2 = *(const float4*)(px + 32); nu3 = *(const float4*)(px + 36);
            nfl = flag[g];
        }

        // ---- cvt x -> bf16 B-frags ----
        uint4 pk0, pk1;
        pk0.x = pack_b2(cu0.x, cu0.y); pk0.y = pack_b2(cu0.z, cu0.w);
        pk0.z = pack_b2(cu1.x, cu1.y); pk0.w = pack_b2(cu1.z, cu1.w);
        pk1.x = pack_b2(cu2.x, cu2.y); pk1.y = pack_b2(cu2.z, cu2.w);
        pk1.z = pack_b2(cu3.x, cu3.y); pk1.w = pack_b2(cu3.z, cu3.w);
        const bf16x8 bx0 = __builtin_bit_cast(bf16x8, pk0);
        const bf16x8 bx1 = __builtin_bit_cast(bf16x8, pk1);

        // ---- GEMM1: h^T = W^T @ x^T ----
        f32x4 accH[4];
#pragma unroll
        for (int nt = 0; nt < 4; ++nt) accH[nt] = (f32x4){0.f, 0.f, 0.f, 0.f};
#pragma unroll
        for (int nt = 0; nt < 4; ++nt)
            accH[nt] = __builtin_amdgcn_mfma_f32_16x16x32_bf16(aw[nt][0], bx0, accH[nt], 0, 0, 0);
#pragma unroll
        for (int nt = 0; nt < 4; ++nt)
            accH[nt] = __builtin_amdgcn_mfma_f32_16x16x32_bf16(aw[nt][1], bx1, accH[nt], 0, 0, 0);
        // lane holds h[node = t*64+wv*16+m][hcol = 16nt+4q+r]

        // ---- h -> wave-private LDS roundtrip (bf16), relayout for GEMM2 ----
        asm volatile("" ::: "memory");
#pragma unroll
        for (int nt = 0; nt < 4; ++nt) {
            uint2 pk;
            pk.x = pack_b2(accH[nt][0], accH[nt][1]);
            pk.y = pack_b2(accH[nt][2], accH[nt][3]);
            *(uint2*)&sH[wv][m][16 * nt + 4 * q] = pk;
        }
        asm volatile("" ::: "memory");
        const bf16x8 a20 = *(const bf16x8*)&sH[wv][m][8 * q];
        const bf16x8 a21 = *(const bf16x8*)&sH[wv][m][32 + 8 * q];

        // ---- GEMM2: t^T = W1^T @ h^T ----
        f32x4 acc20 = b1v0, acc21 = b1v1;
        acc20 = __builtin_amdgcn_mfma_f32_16x16x32_bf16(aw1[0][0], a20, acc20, 0, 0, 0);
        acc20 = __builtin_amdgcn_mfma_f32_16x16x32_bf16(aw1[0][1], a21, acc20, 0, 0, 0);
        acc21 = __builtin_amdgcn_mfma_f32_16x16x32_bf16(aw1[1][0], a20, acc21, 0, 0, 0);
        acc21 = __builtin_amdgcn_mfma_f32_16x16x32_bf16(aw1[1][1], a21, acc21, 0, 0, 0);

        // ---- peak: pp = sum gelu(t)*W2; reduce over 4 q-groups ----
        float pp = 0.f;
#pragma unroll
        for (int r = 0; r < 4; ++r) {
            pp = fmaf(gelu_fast(acc20[r]), w2v0[r], pp);
            pp = fmaf(gelu_fast(acc21[r]), w2v1[r], pp);
        }
        pp += __shfl_xor(pp, 16);
        pp += __shfl_xor(pp, 32);
        const float sg = __builtin_amdgcn_rcpf(1.f + __expf(-(pp + b2s)));
        const float scale = (cfl != 0) ? (1.f + sg) : 0.f;

        // ---- epilogue: out = h*scale + bias ----
        const int g = t * 64 + wv * 16 + m;
        if (g < N) {
            float* po = out + (size_t)g * D + 4 * q;
#pragma unroll
            for (int nt = 0; nt < 4; ++nt) {
                f32x4 o;
#pragma unroll
                for (int r = 0; r < 4; ++r)
                    o[r] = fmaf(accH[nt][r], scale, biasv[nt][r]);
                *(f32x4*)(po + 16 * nt) = o;
            }
        }

        if (!more) break;
        cu0 = nu0; cu1 = nu1; cu2 = nu2; cu3 = nu3; cfl = nfl;
        t = tn;
    }
}

extern "C" void kernel_launch(void* const* d_in, const int* in_sizes, int n_in,
                              void* d_out, int out_size, void* d_ws, size_t ws_size,
                              hipStream_t stream) {
    const float* x    = (const float*)d_in[0];
    const int*   eidx = (const int*)d_in[1];   // [2, E]: first E entries = row
    const float* Wlin = (const float*)d_in[2];
    // d_in[3] att_src, d_in[4] att_dst cancel (segment softmax sums to 1)
    const float* bias = (const float*)d_in[5];
    const float* W1   = (const float*)d_in[6];
    const float* b1   = (const float*)d_in[7];
    const float* W2   = (const float*)d_in[8];
    const float* b2   = (const float*)d_in[9];
    float* out = (float*)d_out;

    const int N = in_sizes[0] / D;
    const int E = in_sizes[1] / 2;

    char* ws = (char*)d_ws;
    unsigned char* flag = (unsigned char*)ws;
    const int nflag4 = (N + 15) / 16;
    const size_t off = (((size_t)nflag4 * 16) + 255) & ~(size_t)255;
    unsigned short* packAW   = (unsigned short*)(ws + off);            // 8192 B
    unsigned short* packAW1  = (unsigned short*)(ws + off + 8192);     // 4096 B
    float*          packBias = (float*)(ws + off + 12288);             // 4096 B
    float*          packB1   = (float*)(ws + off + 16384);             // 2048 B
    float*          packW2   = (float*)(ws + off + 18432);             // 2048 B

    const int ntiles  = (N + 63) / 64;
    const int nblocks = (ntiles < 512) ? ntiles : 512;

    prep_kernel<<<256, 256, 0, stream>>>(Wlin, W1, bias, b1, W2,
                                         (uint4*)flag, nflag4,
                                         packAW, packAW1, packBias, packB1, packW2);
    edge_flag_kernel<<<(E / 4 + 255) / 256, 256, 0, stream>>>(eidx, flag, E);
    gat_mfma5<<<nblocks, 256, 0, stream>>>(x, flag, packAW, packAW1,
                                           packBias, packB1, packW2, b2, out, N, ntiles);
}